// Round 7
// baseline (21498.607 us; speedup 1.0000x reference)
//
#include <hip/hip_runtime.h>
#include <hip/hip_fp16.h>
#include <math.h>

#define CH    4
#define NCH   512            // 2048 / CH
#define KMAX  522            // last event: R_4 chunk 511 at k = 511 + 2 + 8
#define HID   64

typedef __attribute__((ext_vector_type(4))) float f32x4;
typedef __attribute__((ext_vector_type(2))) float f32x2;

__device__ __forceinline__ float sigmoid_(float x) { return 1.0f / (1.0f + __expf(-x)); }
__device__ __forceinline__ float tanh_(float x) {
    float e = __expf(2.0f * x);
    return 1.0f - 2.0f / (e + 1.0f);
}
__device__ __forceinline__ float pack2h(float a, float b) {
    unsigned int ha = (unsigned int)__half_as_ushort(__float2half(a));  // RNE
    unsigned int hb = (unsigned int)__half_as_ushort(__float2half(b));
    return __uint_as_float((hb << 16) | ha);
}
__device__ __forceinline__ f32x2 unp2h(float f) {
    unsigned int u = __float_as_uint(f);
    f32x2 r;
    r.x = __half2float(__ushort_as_half((unsigned short)(u & 0xffffu)));
    r.y = __half2float(__ushort_as_half((unsigned short)(u >> 16)));
    return r;
}

// All 5 LSTM layers, wavefront-pipelined in ONE kernel.
// grid = 256 blocks (1 sample); block = 512 threads (8 waves, 2/SIMD -> 256 VGPR budget).
//   waves 0-4 (R): recurrence for layer l=wave. lane j owns hidden unit j.
//     i,f,o W_hh rows in VGPRs (192); g rows in LDS fp32 (s_wg). At supercycle k,
//     R_l runs chunk c = k-2-2l (4 steps, barrier-free internally).
//     Waves 2,3 additionally compute layer-0 xg rows 0..127 (i,f) from LDS-resident
//     fp32 W_ih0 rows (s_w0) -- they have slack.
//   waves 5-7 (G): xg for rows 128..1279 (layer-0 g,o + layers 1-4 all gates).
//     Weights fp16-packed in the SAME wreg union (6 slots x 32 dwords = 192 regs);
//     math in fp32 (cvt + pk_fma), h stays fp32. Slot j of lane q handles global
//     gate-row flat = 128 + j*192 + q; (wave,slot) is layer-uniform by construction.
//     G_ly computes chunk c at k = c+1+2*ly from s_x (ly=0) or s_hh[ly-1].
//     Wave 5/6 lanes q<45 also stage x chunk k into s_x.
// One __syncthreads per supercycle. Only global traffic in steady state: x reads.
// Schedule: stage x(c)@k=c -> G_0(c)@c+1 -> R_0(c)@c+2 -> G_1(c)@c+3 -> R_1@c+4 ... R_4@c+10.
__global__ __launch_bounds__(512, 2)
void lstm_pipe_kernel(const float* __restrict__ x,          // [256,2048,45]
                      const float* __restrict__ W_ih0,      // [256,45]
                      const float* __restrict__ W_ih_rest,  // [4,256,64]
                      const float* __restrict__ W_hh,       // [5,256,64]
                      const float* __restrict__ b_ih,       // [5,256]
                      const float* __restrict__ b_hh,       // [5,256]
                      float* __restrict__ h_last)           // [256,64] (d_ws)
{
    __shared__ float s_xg[2][5][CH][256];   // 40960 B  xg double buffer
    __shared__ float s_wg[5][16][64][4];    // 81920 B  g-gate W_hh rows (fp32)
    __shared__ float s_hh[4][2][CH][64];    // 8192 B   h handoff l -> l+1
    __shared__ float s_h[5][64];            // 1280 B   current h per layer
    __shared__ float s_x[2][CH][48];        // 1536 B   staged x chunk (45 + 3 zero pad)
    __shared__ float s_w0[128][49];         // 25088 B  layer-0 rows 0..127 fp32 (stride 49: bank-spread)
    // total 158976 B -> 1 block/CU

    const int tid  = threadIdx.x;
    const int wave = tid >> 6;
    const int lane = tid & 63;
    const int s    = blockIdx.x;
    const float* x_s = x + (size_t)s * 2048 * 45;

    // ---- init: h0, x pad cols, s_w0 ----
    if (tid < 5 * 64) (&s_h[0][0])[tid] = 0.f;
    if (tid < 2 * CH * 3) {
        int b = tid / (CH * 3), rem = tid % (CH * 3);
        s_x[b][rem / 3][45 + rem % 3] = 0.f;
    }
    for (int i = tid; i < 128 * 49; i += 512) {
        int r = i / 49, kk = i - r * 49;
        (&s_w0[0][0])[i] = (kk < 45) ? W_ih0[r * 45 + kk] : 0.f;
    }

    // ---- union register file: R = 48 f32x4 of W_hh i|f|o rows; G = 6 slots x 8 f32x4 of packed fp16 ----
    f32x4 wreg[48];
    float sbias[6] = {0.f, 0.f, 0.f, 0.f, 0.f, 0.f};
    float stream_bias = 0.f;
    float cc = 0.f;   // cell state (R waves)

    if (wave < 5) {
        const float* Wl = W_hh + (size_t)wave * 256 * 64;
#pragma unroll
        for (int k4 = 0; k4 < 16; ++k4) {
            wreg[k4]      = *(const f32x4*)&Wl[(size_t)(lane)       * 64 + 4 * k4];  // i
            wreg[16 + k4] = *(const f32x4*)&Wl[(size_t)(64 + lane)  * 64 + 4 * k4];  // f
            wreg[32 + k4] = *(const f32x4*)&Wl[(size_t)(192 + lane) * 64 + 4 * k4];  // o
            *(f32x4*)&s_wg[wave][k4][lane][0] =
                *(const f32x4*)&Wl[(size_t)(128 + lane) * 64 + 4 * k4];              // g -> LDS
        }
        if (wave == 2 || wave == 3) {
            const int rl = (wave - 2) * 64 + lane;    // layer-0 gate row 0..127
            stream_bias = b_ih[rl] + b_hh[rl];
        }
    } else {
        const int q = (wave - 5) * 64 + lane;         // 0..191
#pragma unroll
        for (int j = 0; j < 6; ++j) {
            const int flat = 128 + j * 192 + q;       // 128..1279, each exactly once
            const int ly   = flat >> 8;
            const int row  = flat & 255;
            const float* wsrc = (ly == 0) ? (W_ih0 + (size_t)row * 45)
                                          : (W_ih_rest + ((size_t)(ly - 1) * 256 + row) * 64);
            const int K = (ly == 0) ? 45 : 64;
#pragma unroll
            for (int d = 0; d < 8; ++d) {
                float v0 = (8 * d + 0 < K) ? wsrc[8 * d + 0] : 0.f;
                float v1 = (8 * d + 1 < K) ? wsrc[8 * d + 1] : 0.f;
                float v2 = (8 * d + 2 < K) ? wsrc[8 * d + 2] : 0.f;
                float v3 = (8 * d + 3 < K) ? wsrc[8 * d + 3] : 0.f;
                float v4 = (8 * d + 4 < K) ? wsrc[8 * d + 4] : 0.f;
                float v5 = (8 * d + 5 < K) ? wsrc[8 * d + 5] : 0.f;
                float v6 = (8 * d + 6 < K) ? wsrc[8 * d + 6] : 0.f;
                float v7 = (8 * d + 7 < K) ? wsrc[8 * d + 7] : 0.f;
                f32x4 pw = { pack2h(v0, v1), pack2h(v2, v3), pack2h(v4, v5), pack2h(v6, v7) };
                wreg[j * 8 + d] = pw;
            }
            sbias[j] = b_ih[ly * 256 + row] + b_hh[ly * 256 + row];
        }
    }
    __syncthreads();

    // ---- supercycle loop ----
    for (int k = 0; k < KMAX; ++k) {
        if (wave < 5) {
            // ---------------- R: recurrence, layer l, chunk c ----------------
            const int l = wave;
            const int c = k - 2 - 2 * l;
            if (c >= 0 && c < NCH) {
                const int buf = c & 1;
#pragma unroll
                for (int t = 0; t < CH; ++t) {
                    const float xi  = s_xg[buf][l][t][lane];
                    const float xf  = s_xg[buf][l][t][64 + lane];
                    const float xgv = s_xg[buf][l][t][128 + lane];
                    const float xo  = s_xg[buf][l][t][192 + lane];
                    f32x4 ai = {0,0,0,0}, af = {0,0,0,0}, ag = {0,0,0,0}, ao = {0,0,0,0};
#pragma unroll
                    for (int k4 = 0; k4 < 16; ++k4) {
                        const f32x4 h4  = *(const f32x4*)&s_h[l][4 * k4];          // uniform bcast
                        const f32x4 wg4 = *(const f32x4*)&s_wg[l][k4][lane][0];    // dense b128
                        ai += wreg[k4]      * h4;
                        af += wreg[16 + k4] * h4;
                        ao += wreg[32 + k4] * h4;
                        ag += wg4 * h4;
                    }
                    const float pi = xi  + ((ai.x + ai.y) + (ai.z + ai.w));
                    const float pf = xf  + ((af.x + af.y) + (af.z + af.w));
                    const float pg = xgv + ((ag.x + ag.y) + (ag.z + ag.w));
                    const float po = xo  + ((ao.x + ao.y) + (ao.z + ao.w));
                    const float I = sigmoid_(pi);
                    const float F = sigmoid_(pf);
                    const float G = tanh_(pg);
                    const float O = sigmoid_(po);
                    cc = fmaf(F, cc, I * G);
                    const float h = O * tanh_(cc);
                    s_h[l][lane] = h;                               // own next-step bcast
                    if (l < 4) s_hh[l][buf][t][lane] = h;           // next layer's GEMM input
                    else if (c == NCH - 1 && t == CH - 1) h_last[(size_t)s * 64 + lane] = h;
                }
            }
            // ---- waves 2,3: layer-0 xg rows 0..127 (i,f) from LDS fp32 weights ----
            if (wave == 2 || wave == 3) {
                const int cs = k - 1;
                if (cs >= 0 && cs < NCH) {
                    const int bufs = cs & 1;
                    const int rl = (wave - 2) * 64 + lane;
                    f32x2 a0 = {0,0}, a1 = {0,0}, a2 = {0,0}, a3 = {0,0};
#pragma unroll
                    for (int k4 = 0; k4 < 12; ++k4) {
                        const f32x2 wA = { s_w0[rl][4 * k4 + 0], s_w0[rl][4 * k4 + 1] };
                        const f32x2 wB = { s_w0[rl][4 * k4 + 2], s_w0[rl][4 * k4 + 3] };
                        const f32x4 h0 = *(const f32x4*)&s_x[bufs][0][4 * k4];
                        const f32x4 h1 = *(const f32x4*)&s_x[bufs][1][4 * k4];
                        const f32x4 h2 = *(const f32x4*)&s_x[bufs][2][4 * k4];
                        const f32x4 h3 = *(const f32x4*)&s_x[bufs][3][4 * k4];
                        a0 += wA * (f32x2){h0.x, h0.y} + wB * (f32x2){h0.z, h0.w};
                        a1 += wA * (f32x2){h1.x, h1.y} + wB * (f32x2){h1.z, h1.w};
                        a2 += wA * (f32x2){h2.x, h2.y} + wB * (f32x2){h2.z, h2.w};
                        a3 += wA * (f32x2){h3.x, h3.y} + wB * (f32x2){h3.z, h3.w};
                    }
                    s_xg[bufs][0][0][rl] = stream_bias + a0.x + a0.y;
                    s_xg[bufs][0][1][rl] = stream_bias + a1.x + a1.y;
                    s_xg[bufs][0][2][rl] = stream_bias + a2.x + a2.y;
                    s_xg[bufs][0][3][rl] = stream_bias + a3.x + a3.y;
                }
            }
        } else {
            // ---------------- G: staging + fp16-weight GEMM slots ----------------
            const int q = (wave - 5) * 64 + lane;
            if (k < NCH && q < 45) {       // stage x chunk k (contiguous 180 floats, 16B aligned)
                const float4 v = *(const float4*)(x_s + (size_t)k * 180 + q * 4);
                const int b = k & 1;
                const int e0 = 4 * q;
                s_x[b][(e0 + 0) / 45][(e0 + 0) % 45] = v.x;
                s_x[b][(e0 + 1) / 45][(e0 + 1) % 45] = v.y;
                s_x[b][(e0 + 2) / 45][(e0 + 2) % 45] = v.z;
                s_x[b][(e0 + 3) / 45][(e0 + 3) % 45] = v.w;
            }
#pragma unroll
            for (int j = 0; j < 6; ++j) {
                const int flat = 128 + j * 192 + q;
                const int ly   = flat >> 8;
                const int row  = flat & 255;
                const int c    = k - 1 - 2 * ly;
                if (c >= 0 && c < NCH) {
                    const int buf = c & 1;
                    const float* hsrc = (ly == 0) ? &s_x[buf][0][0] : &s_hh[ly - 1][buf][0][0];
                    const int hstr    = (ly == 0) ? 48 : 64;
                    const int K4      = (ly == 0) ? 12 : 16;
                    f32x2 a0 = {0,0}, a1 = {0,0}, a2 = {0,0}, a3 = {0,0};
#pragma unroll
                    for (int k4 = 0; k4 < 16; ++k4) {
                        if (k4 < K4) {
                            const f32x2 wA = unp2h(wreg[j * 8 + (k4 >> 1)][2 * (k4 & 1) + 0]);
                            const f32x2 wB = unp2h(wreg[j * 8 + (k4 >> 1)][2 * (k4 & 1) + 1]);
                            const f32x4 h0 = *(const f32x4*)&hsrc[0 * hstr + 4 * k4];  // uniform bcast
                            const f32x4 h1 = *(const f32x4*)&hsrc[1 * hstr + 4 * k4];
                            const f32x4 h2 = *(const f32x4*)&hsrc[2 * hstr + 4 * k4];
                            const f32x4 h3 = *(const f32x4*)&hsrc[3 * hstr + 4 * k4];
                            a0 += wA * (f32x2){h0.x, h0.y} + wB * (f32x2){h0.z, h0.w};
                            a1 += wA * (f32x2){h1.x, h1.y} + wB * (f32x2){h1.z, h1.w};
                            a2 += wA * (f32x2){h2.x, h2.y} + wB * (f32x2){h2.z, h2.w};
                            a3 += wA * (f32x2){h3.x, h3.y} + wB * (f32x2){h3.z, h3.w};
                        }
                    }
                    s_xg[buf][ly][0][row] = sbias[j] + a0.x + a0.y;
                    s_xg[buf][ly][1][row] = sbias[j] + a1.x + a1.y;
                    s_xg[buf][ly][2][row] = sbias[j] + a2.x + a2.y;
                    s_xg[buf][ly][3][row] = sbias[j] + a3.x + a3.y;
                }
            }
        }
        __syncthreads();
    }
}

// MLP head: features = gelu(last @ Wl^T + bl); out = relu(features @ Wo^T + bo)
// d_out layout: out[256*4] first, then features[256*128].
__global__ __launch_bounds__(128)
void head_kernel(const float* __restrict__ h_last,  // [256, 64]
                 const float* __restrict__ Wl,      // [128, 64]
                 const float* __restrict__ bl,      // [128]
                 const float* __restrict__ Wo,      // [4, 128]
                 const float* __restrict__ bo,      // [4]
                 float* __restrict__ d_out)
{
    __shared__ float s_last[HID];
    __shared__ float s_feat[128];
    const int s = blockIdx.x;
    const int j = threadIdx.x;

    if (j < HID) s_last[j] = h_last[(size_t)s * HID + j];
    __syncthreads();

    float acc = bl[j];
#pragma unroll
    for (int k = 0; k < HID; ++k)
        acc = fmaf(s_last[k], Wl[j * HID + k], acc);
    float f = 0.5f * acc * (1.0f + erff(acc * 0.70710678118654752440f));
    d_out[256 * 4 + s * 128 + j] = f;
    s_feat[j] = f;
    __syncthreads();

    if (j < 4) {
        float a = bo[j];
#pragma unroll
        for (int k = 0; k < 128; ++k)
            a = fmaf(s_feat[k], Wo[j * 128 + k], a);
        d_out[s * 4 + j] = fmaxf(a, 0.0f);
    }
}

extern "C" void kernel_launch(void* const* d_in, const int* in_sizes, int n_in,
                              void* d_out, int out_size, void* d_ws, size_t ws_size,
                              hipStream_t stream)
{
    const float* x         = (const float*)d_in[0];  // [256, 2048, 45]
    const float* W_ih0     = (const float*)d_in[1];  // [256, 45]
    const float* W_ih_rest = (const float*)d_in[2];  // [4, 256, 64]
    const float* W_hh      = (const float*)d_in[3];  // [5, 256, 64]
    const float* b_ih      = (const float*)d_in[4];  // [5, 256]
    const float* b_hh      = (const float*)d_in[5];  // [5, 256]
    const float* Wl        = (const float*)d_in[6];  // [128, 64]
    const float* bl        = (const float*)d_in[7];  // [128]
    const float* Wo        = (const float*)d_in[8];  // [4, 128]
    const float* bo        = (const float*)d_in[9];  // [4]

    float* h_last = (float*)d_ws;   // [256, 64] fp32 = 64 KB

    lstm_pipe_kernel<<<256, 512, 0, stream>>>(
        x, W_ih0, W_ih_rest, W_hh, b_ih, b_hh, h_last);
    head_kernel<<<256, 128, 0, stream>>>(h_last, Wl, bl, Wo, bo, (float*)d_out);
}

// Round 8
// 18109.572 us; speedup vs baseline: 1.1871x; 1.1871x over previous
//
#include <hip/hip_runtime.h>
#include <hip/hip_fp16.h>
#include <math.h>

#define CH    4
#define NCH   512            // 2048 / CH
#define KMAX  522            // last event: R_4 chunk 511 at k = 511 + 2 + 8
#define HID   64

typedef __attribute__((ext_vector_type(4))) float f32x4;
typedef __attribute__((ext_vector_type(2))) float f32x2;

__device__ __forceinline__ float sigmoid_(float x) { return 1.0f / (1.0f + __expf(-x)); }
__device__ __forceinline__ float tanh_(float x) {
    float e = __expf(2.0f * x);
    return 1.0f - 2.0f / (e + 1.0f);
}
__device__ __forceinline__ float pack2h(float a, float b) {
    unsigned int ha = (unsigned int)__half_as_ushort(__float2half(a));  // RNE
    unsigned int hb = (unsigned int)__half_as_ushort(__float2half(b));
    return __uint_as_float((hb << 16) | ha);
}
__device__ __forceinline__ f32x2 unp2h(float f) {
    __half2 h2 = *reinterpret_cast<__half2*>(&f);
    float2 r = __half22float2(h2);               // 2x v_cvt_f32_f16 (lo, hi)
    return (f32x2){r.x, r.y};
}

// All 5 LSTM layers, wavefront-pipelined in ONE kernel.
// grid = 256 blocks (1 sample); block = 512 threads (8 waves).
// amdgpu_waves_per_eu(2,2): EXACTLY 2 waves/EU -> 256-VGPR budget. (Round 7
// used __launch_bounds__(512,2) and the compiler budgeted 128 regs -> the
// 192-dword weight union spilled -> 22GB scratch traffic. Round 8 pins the
// occupancy AND shrinks the R-wave demand to 160 regs.)
//   waves 0-4 (R): recurrence for layer l=wave. lane j owns hidden unit j.
//     i,f W_hh rows fp32 in VGPRs (128); o row fp16-packed in VGPRs (32);
//     g rows in LDS fp32 (s_wg). At supercycle k, R_l runs chunk c = k-2-2l
//     (4 steps, barrier-free internally).
//     Waves 2,3 additionally compute layer-0 xg rows 0..127 (i,f) from
//     LDS-resident fp32 W_ih0 rows (s_w0) -- they have slack.
//   waves 5-7 (G): xg for rows 128..1279 (layer-0 g,o + layers 1-4 all gates).
//     Weights fp16-packed in the SAME wreg union (6 slots x 8 f32x4 = 192);
//     math in fp32 (cvt + pk_fma), h stays fp32. Slot j of lane q handles
//     global gate-row flat = 128 + j*192 + q; (wave,slot) is layer-uniform
//     (64-aligned 64-long ranges never cross a 256 boundary).
//     G_ly computes chunk c at k = c+1+2*ly from s_x (ly=0) or s_hh[ly-1].
//     Wave-5 lanes q<45 also stage x chunk k into s_x.
// One __syncthreads per supercycle. Only steady-state global traffic: x reads.
// Schedule: stage x(c)@k=c -> G_0(c)@c+1 -> R_0(c)@c+2 -> G_1(c)@c+3 -> ... R_4@c+10.
__global__ __attribute__((amdgpu_waves_per_eu(2, 2))) __launch_bounds__(512)
void lstm_pipe_kernel(const float* __restrict__ x,          // [256,2048,45]
                      const float* __restrict__ W_ih0,      // [256,45]
                      const float* __restrict__ W_ih_rest,  // [4,256,64]
                      const float* __restrict__ W_hh,       // [5,256,64]
                      const float* __restrict__ b_ih,       // [5,256]
                      const float* __restrict__ b_hh,       // [5,256]
                      float* __restrict__ h_last)           // [256,64] (d_ws)
{
    __shared__ float s_xg[2][5][CH][256];   // 40960 B  xg double buffer
    __shared__ float s_wg[5][16][64][4];    // 81920 B  g-gate W_hh rows (fp32)
    __shared__ float s_hh[4][2][CH][64];    // 8192 B   h handoff l -> l+1
    __shared__ float s_h[5][64];            // 1280 B   current h per layer
    __shared__ float s_x[2][CH][48];        // 1536 B   staged x chunk (45 + 3 zero pad)
    __shared__ float s_w0[128][49];         // 25088 B  layer-0 rows 0..127 fp32 (stride 49)
    // total 158976 B -> 1 block/CU

    const int tid  = threadIdx.x;
    const int wave = tid >> 6;
    const int lane = tid & 63;
    const int s    = blockIdx.x;
    const float* x_s = x + (size_t)s * 2048 * 45;

    // ---- init: h0, x pad cols, s_w0 ----
    if (tid < 5 * 64) (&s_h[0][0])[tid] = 0.f;
    if (tid < 2 * CH * 3) {
        int b = tid / (CH * 3), rem = tid % (CH * 3);
        s_x[b][rem / 3][45 + rem % 3] = 0.f;
    }
    for (int i = tid; i < 128 * 49; i += 512) {
        int r = i / 49, kk = i - r * 49;
        (&s_w0[0][0])[i] = (kk < 45) ? W_ih0[r * 45 + kk] : 0.f;
    }

    // ---- union register file:
    //   R: [0..15]=i rows fp32, [16..31]=f rows fp32, [32..39]=o row fp16-packed
    //   G: [0..47] = 6 slots x 8 f32x4 of fp16-packed W_ih rows
    f32x4 wreg[48];
    float sbias[6] = {0.f, 0.f, 0.f, 0.f, 0.f, 0.f};
    float stream_bias = 0.f;
    float cc = 0.f;   // cell state (R waves)

    if (wave < 5) {
        const float* Wl = W_hh + (size_t)wave * 256 * 64;
#pragma unroll
        for (int k4 = 0; k4 < 16; ++k4) {
            wreg[k4]      = *(const f32x4*)&Wl[(size_t)(lane)      * 64 + 4 * k4];   // i
            wreg[16 + k4] = *(const f32x4*)&Wl[(size_t)(64 + lane) * 64 + 4 * k4];   // f
            *(f32x4*)&s_wg[wave][k4][lane][0] =
                *(const f32x4*)&Wl[(size_t)(128 + lane) * 64 + 4 * k4];              // g -> LDS
        }
#pragma unroll
        for (int d = 0; d < 8; ++d) {                                                // o, fp16
            const float* o = &Wl[(size_t)(192 + lane) * 64 + 8 * d];
            f32x4 pw = { pack2h(o[0], o[1]), pack2h(o[2], o[3]),
                         pack2h(o[4], o[5]), pack2h(o[6], o[7]) };
            wreg[32 + d] = pw;
        }
        if (wave == 2 || wave == 3) {
            const int rl = (wave - 2) * 64 + lane;    // layer-0 gate row 0..127
            stream_bias = b_ih[rl] + b_hh[rl];
        }
    } else {
        const int q = (wave - 5) * 64 + lane;         // 0..191
#pragma unroll
        for (int j = 0; j < 6; ++j) {
            const int flat = 128 + j * 192 + q;       // 128..1279, each exactly once
            const int ly   = flat >> 8;
            const int row  = flat & 255;
            const float* wsrc = (ly == 0) ? (W_ih0 + (size_t)row * 45)
                                          : (W_ih_rest + ((size_t)(ly - 1) * 256 + row) * 64);
            const int K = (ly == 0) ? 45 : 64;
#pragma unroll
            for (int d = 0; d < 8; ++d) {
                float v0 = (8 * d + 0 < K) ? wsrc[8 * d + 0] : 0.f;
                float v1 = (8 * d + 1 < K) ? wsrc[8 * d + 1] : 0.f;
                float v2 = (8 * d + 2 < K) ? wsrc[8 * d + 2] : 0.f;
                float v3 = (8 * d + 3 < K) ? wsrc[8 * d + 3] : 0.f;
                float v4 = (8 * d + 4 < K) ? wsrc[8 * d + 4] : 0.f;
                float v5 = (8 * d + 5 < K) ? wsrc[8 * d + 5] : 0.f;
                float v6 = (8 * d + 6 < K) ? wsrc[8 * d + 6] : 0.f;
                float v7 = (8 * d + 7 < K) ? wsrc[8 * d + 7] : 0.f;
                f32x4 pw = { pack2h(v0, v1), pack2h(v2, v3), pack2h(v4, v5), pack2h(v6, v7) };
                wreg[j * 8 + d] = pw;
            }
            sbias[j] = b_ih[ly * 256 + row] + b_hh[ly * 256 + row];
        }
    }
    __syncthreads();

    // ---- supercycle loop ----
    for (int k = 0; k < KMAX; ++k) {
        if (wave < 5) {
            // ---------------- R: recurrence, layer l, chunk c ----------------
            const int l = wave;
            const int c = k - 2 - 2 * l;
            if (c >= 0 && c < NCH) {
                const int buf = c & 1;
#pragma unroll
                for (int t = 0; t < CH; ++t) {
                    const float xi  = s_xg[buf][l][t][lane];
                    const float xf  = s_xg[buf][l][t][64 + lane];
                    const float xgv = s_xg[buf][l][t][128 + lane];
                    const float xo  = s_xg[buf][l][t][192 + lane];
                    f32x4 ai = {0,0,0,0}, af = {0,0,0,0}, ag = {0,0,0,0};
                    f32x2 aoA = {0,0}, aoB = {0,0};
#pragma unroll
                    for (int k4 = 0; k4 < 16; ++k4) {
                        const f32x4 h4  = *(const f32x4*)&s_h[l][4 * k4];          // uniform bcast
                        const f32x4 wg4 = *(const f32x4*)&s_wg[l][k4][lane][0];    // dense b128
                        ai += wreg[k4]      * h4;
                        af += wreg[16 + k4] * h4;
                        ag += wg4 * h4;
                        const f32x2 oA = unp2h(wreg[32 + (k4 >> 1)][(k4 & 1) * 2 + 0]);
                        const f32x2 oB = unp2h(wreg[32 + (k4 >> 1)][(k4 & 1) * 2 + 1]);
                        aoA += oA * (f32x2){h4.x, h4.y};
                        aoB += oB * (f32x2){h4.z, h4.w};
                    }
                    const float pi = xi  + ((ai.x + ai.y) + (ai.z + ai.w));
                    const float pf = xf  + ((af.x + af.y) + (af.z + af.w));
                    const float pg = xgv + ((ag.x + ag.y) + (ag.z + ag.w));
                    const float po = xo  + ((aoA.x + aoA.y) + (aoB.x + aoB.y));
                    const float I = sigmoid_(pi);
                    const float F = sigmoid_(pf);
                    const float G = tanh_(pg);
                    const float O = sigmoid_(po);
                    cc = fmaf(F, cc, I * G);
                    const float h = O * tanh_(cc);
                    s_h[l][lane] = h;                               // own next-step bcast
                    if (l < 4) s_hh[l][buf][t][lane] = h;           // next layer's GEMM input
                    else if (c == NCH - 1 && t == CH - 1) h_last[(size_t)s * 64 + lane] = h;
                }
            }
            // ---- waves 2,3: layer-0 xg rows 0..127 (i,f) from LDS fp32 weights ----
            if (wave == 2 || wave == 3) {
                const int cs = k - 1;
                if (cs >= 0 && cs < NCH) {
                    const int bufs = cs & 1;
                    const int rl = (wave - 2) * 64 + lane;
                    f32x2 a0 = {0,0}, a1 = {0,0}, a2 = {0,0}, a3 = {0,0};
#pragma unroll
                    for (int k4 = 0; k4 < 12; ++k4) {
                        const f32x2 wA = { s_w0[rl][4 * k4 + 0], s_w0[rl][4 * k4 + 1] };
                        const f32x2 wB = { s_w0[rl][4 * k4 + 2], s_w0[rl][4 * k4 + 3] };
                        const f32x4 h0 = *(const f32x4*)&s_x[bufs][0][4 * k4];
                        const f32x4 h1 = *(const f32x4*)&s_x[bufs][1][4 * k4];
                        const f32x4 h2 = *(const f32x4*)&s_x[bufs][2][4 * k4];
                        const f32x4 h3 = *(const f32x4*)&s_x[bufs][3][4 * k4];
                        a0 += wA * (f32x2){h0.x, h0.y} + wB * (f32x2){h0.z, h0.w};
                        a1 += wA * (f32x2){h1.x, h1.y} + wB * (f32x2){h1.z, h1.w};
                        a2 += wA * (f32x2){h2.x, h2.y} + wB * (f32x2){h2.z, h2.w};
                        a3 += wA * (f32x2){h3.x, h3.y} + wB * (f32x2){h3.z, h3.w};
                    }
                    s_xg[bufs][0][0][rl] = stream_bias + a0.x + a0.y;
                    s_xg[bufs][0][1][rl] = stream_bias + a1.x + a1.y;
                    s_xg[bufs][0][2][rl] = stream_bias + a2.x + a2.y;
                    s_xg[bufs][0][3][rl] = stream_bias + a3.x + a3.y;
                }
            }
        } else {
            // ---------------- G: staging + fp16-weight GEMM slots ----------------
            const int q = (wave - 5) * 64 + lane;
            if (k < NCH && q < 45) {       // stage x chunk k (contiguous 180 floats, 16B aligned)
                const float4 v = *(const float4*)(x_s + (size_t)k * 180 + q * 4);
                const int b = k & 1;
                const int e0 = 4 * q;
                s_x[b][(e0 + 0) / 45][(e0 + 0) % 45] = v.x;
                s_x[b][(e0 + 1) / 45][(e0 + 1) % 45] = v.y;
                s_x[b][(e0 + 2) / 45][(e0 + 2) % 45] = v.z;
                s_x[b][(e0 + 3) / 45][(e0 + 3) % 45] = v.w;
            }
#pragma unroll
            for (int j = 0; j < 6; ++j) {
                const int flat = 128 + j * 192 + q;
                const int ly   = flat >> 8;
                const int row  = flat & 255;
                const int c    = k - 1 - 2 * ly;
                if (c >= 0 && c < NCH) {
                    const int buf = c & 1;
                    const float* hsrc = (ly == 0) ? &s_x[buf][0][0] : &s_hh[ly - 1][buf][0][0];
                    const int hstr    = (ly == 0) ? 48 : 64;
                    const int K4      = (ly == 0) ? 12 : 16;
                    f32x2 a0 = {0,0}, a1 = {0,0}, a2 = {0,0}, a3 = {0,0};
#pragma unroll
                    for (int k4 = 0; k4 < 16; ++k4) {
                        if (k4 < K4) {
                            const f32x2 wA = unp2h(wreg[j * 8 + (k4 >> 1)][2 * (k4 & 1) + 0]);
                            const f32x2 wB = unp2h(wreg[j * 8 + (k4 >> 1)][2 * (k4 & 1) + 1]);
                            const f32x4 h0 = *(const f32x4*)&hsrc[0 * hstr + 4 * k4];
                            const f32x4 h1 = *(const f32x4*)&hsrc[1 * hstr + 4 * k4];
                            const f32x4 h2 = *(const f32x4*)&hsrc[2 * hstr + 4 * k4];
                            const f32x4 h3 = *(const f32x4*)&hsrc[3 * hstr + 4 * k4];
                            a0 += wA * (f32x2){h0.x, h0.y} + wB * (f32x2){h0.z, h0.w};
                            a1 += wA * (f32x2){h1.x, h1.y} + wB * (f32x2){h1.z, h1.w};
                            a2 += wA * (f32x2){h2.x, h2.y} + wB * (f32x2){h2.z, h2.w};
                            a3 += wA * (f32x2){h3.x, h3.y} + wB * (f32x2){h3.z, h3.w};
                        }
                    }
                    s_xg[buf][ly][0][row] = sbias[j] + a0.x + a0.y;
                    s_xg[buf][ly][1][row] = sbias[j] + a1.x + a1.y;
                    s_xg[buf][ly][2][row] = sbias[j] + a2.x + a2.y;
                    s_xg[buf][ly][3][row] = sbias[j] + a3.x + a3.y;
                }
            }
        }
        __syncthreads();
    }
}

// MLP head: features = gelu(last @ Wl^T + bl); out = relu(features @ Wo^T + bo)
// d_out layout: out[256*4] first, then features[256*128].
__global__ __launch_bounds__(128)
void head_kernel(const float* __restrict__ h_last,  // [256, 64]
                 const float* __restrict__ Wl,      // [128, 64]
                 const float* __restrict__ bl,      // [128]
                 const float* __restrict__ Wo,      // [4, 128]
                 const float* __restrict__ bo,      // [4]
                 float* __restrict__ d_out)
{
    __shared__ float s_last[HID];
    __shared__ float s_feat[128];
    const int s = blockIdx.x;
    const int j = threadIdx.x;

    if (j < HID) s_last[j] = h_last[(size_t)s * HID + j];
    __syncthreads();

    float acc = bl[j];
#pragma unroll
    for (int k = 0; k < HID; ++k)
        acc = fmaf(s_last[k], Wl[j * HID + k], acc);
    float f = 0.5f * acc * (1.0f + erff(acc * 0.70710678118654752440f));
    d_out[256 * 4 + s * 128 + j] = f;
    s_feat[j] = f;
    __syncthreads();

    if (j < 4) {
        float a = bo[j];
#pragma unroll
        for (int k = 0; k < 128; ++k)
            a = fmaf(s_feat[k], Wo[j * 128 + k], a);
        d_out[s * 4 + j] = fmaxf(a, 0.0f);
    }
}

extern "C" void kernel_launch(void* const* d_in, const int* in_sizes, int n_in,
                              void* d_out, int out_size, void* d_ws, size_t ws_size,
                              hipStream_t stream)
{
    const float* x         = (const float*)d_in[0];  // [256, 2048, 45]
    const float* W_ih0     = (const float*)d_in[1];  // [256, 45]
    const float* W_ih_rest = (const float*)d_in[2];  // [4, 256, 64]
    const float* W_hh      = (const float*)d_in[3];  // [5, 256, 64]
    const float* b_ih      = (const float*)d_in[4];  // [5, 256]
    const float* b_hh      = (const float*)d_in[5];  // [5, 256]
    const float* Wl        = (const float*)d_in[6];  // [128, 64]
    const float* bl        = (const float*)d_in[7];  // [128]
    const float* Wo        = (const float*)d_in[8];  // [4, 128]
    const float* bo        = (const float*)d_in[9];  // [4]

    float* h_last = (float*)d_ws;   // [256, 64] fp32 = 64 KB

    lstm_pipe_kernel<<<256, 512, 0, stream>>>(
        x, W_ih0, W_ih_rest, W_hh, b_ih, b_hh, h_last);
    head_kernel<<<256, 128, 0, stream>>>(h_last, Wl, bl, Wo, bo, (float*)d_out);
}

// Round 9
// 5649.086 us; speedup vs baseline: 3.8057x; 3.2058x over previous
//
#include <hip/hip_runtime.h>
#include <hip/hip_fp16.h>
#include <math.h>

#define NCH   1024            // 2048 timesteps / CH=2
#define KMAX  1034            // last event: R4 chunk 1023 at k = 1023+10
#define HID   64
typedef unsigned int uint;
typedef __attribute__((ext_vector_type(2))) _Float16 h2t;

__device__ __forceinline__ float sigmoid_(float x){ return 1.0f/(1.0f+__expf(-x)); }
__device__ __forceinline__ float tanh_(float x){ float e=__expf(2.0f*x); return 1.0f-2.0f/(e+1.0f); }

__device__ __forceinline__ float fdot2_(uint w, uint h, float acc){
#if __has_builtin(__builtin_amdgcn_fdot2)
    return __builtin_amdgcn_fdot2(__builtin_bit_cast(h2t,w), __builtin_bit_cast(h2t,h), acc, false);
#else
    __half2 wv = *reinterpret_cast<const __half2*>(&w);
    __half2 hv = *reinterpret_cast<const __half2*>(&h);
    float2 wf = __half22float2(wv), hf = __half22float2(hv);
    return fmaf(wf.x, hf.x, fmaf(wf.y, hf.y, acc));
#endif
}
__device__ __forceinline__ uint packh(float a, float b){
    uint ha = (uint)__half_as_ushort(__float2half(a));   // RNE
    uint hb = (uint)__half_as_ushort(__float2half(b));
    return (hb<<16)|ha;
}
__device__ __forceinline__ uint4 pack8(const float* p){
    return make_uint4(packh(p[0],p[1]), packh(p[2],p[3]), packh(p[4],p[5]), packh(p[6],p[7]));
}

// 8 fdot2 into accumulator A: hi pairs + lo (compensation) pairs, same weights.
#define DOT8(A, W, HH, HL) do{ \
    A=fdot2_((W).x,(HH).x,A); A=fdot2_((W).y,(HH).y,A); \
    A=fdot2_((W).z,(HH).z,A); A=fdot2_((W).w,(HH).w,A); \
    A=fdot2_((W).x,(HL).x,A); A=fdot2_((W).y,(HL).y,A); \
    A=fdot2_((W).z,(HL).z,A); A=fdot2_((W).w,(HL).w,A); }while(0)

// All 5 LSTM layers, wavefront-pipelined, ONE kernel.
// grid = 256 blocks (1 sample), block = 256 threads (4 waves, PROVEN 256-VGPR budget:
// r4..r8 establish cap = 65536/block_threads; occupancy attributes are ignored).
// CH=2 steps/chunk, 1034 supercycles, one __syncthreads each.
//   w0: recurrence L0+L1 (two chains interleave -> stalls hide) + xg[L4] rows 0-127 (LDS W)
//   w1: recurrence L2+L3 + xg[L4] rows 128-255 (LDS W)
//   w2: recurrence L4 + stage x + xg[L0] all rows (reg W, K=45) + xg[L2] rows 128-255 (LDS W)
//   w3: xg[L1] all rows (reg W) + xg[L2] rows 0-127 (reg W) + xg[L3] all rows (LDS W)
// Weights fp16-RNE: W_hh{i,f,g} in VGPRs (192 dw), W_hh{o} + 10 W_ih row-groups in LDS.
// h and x are hi+lo fp16 compensated (~fp29) -> only weight rounding contributes error.
// Schedule: stage x(c)@k=c; G_l(c)@k=c+1+2l; R_l(c)@k=c+2+2l. All dbuf parities verified.
__global__ __attribute__((amdgpu_waves_per_eu(1,1))) __launch_bounds__(256)
void lstm_pipe4(const float* __restrict__ x,          // [256,2048,45]
                const float* __restrict__ W_ih0,      // [256,45]
                const float* __restrict__ W_ih_rest,  // [4,256,64]
                const float* __restrict__ W_hh,       // [5,256,64]
                const float* __restrict__ b_ih,       // [5,256]
                const float* __restrict__ b_hh,       // [5,256]
                float* __restrict__ h_last)           // [256,64] (d_ws)
{
    __shared__ float s_xg[2][5][2][256];        // 20480 B  xg double buffer (fp32)
    __shared__ uint  s_wo [5][8][64][4];        // 40960 B  W_hh o-gate, fp16 packed
    __shared__ uint  s_wih[10][8][64][4];       // 81920 B  W_ih groups 10..19, fp16 packed
    __shared__ uint  s_hhhi[4][2][2][32];       //  2048 B  h handoff hi
    __shared__ uint  s_hhlo[4][2][2][32];       //  2048 B  h handoff lo
    __shared__ uint  s_h16hi[5][32];            //   640 B  per-layer running h hi
    __shared__ uint  s_h16lo[5][32];            //   640 B  per-layer running h lo
    __shared__ uint  s_xhi[2][2][24];           //   384 B  staged x hi (48 halfs, 45+3 pad)
    __shared__ uint  s_xlo[2][2][24];           //   384 B  staged x lo
    // total 149504 B -> 1 block/CU

    const int tid  = threadIdx.x;
    const int wave = tid >> 6;
    const int lane = tid & 63;
    const int sm   = blockIdx.x;
    const float* x_s = x + (size_t)sm * 2048 * 45;
    float* hlast_g = h_last + (size_t)sm * HID;

    uint4 wU[48];          // per-wave weight register file (192 dwords), all static-indexed
    float b0=0,b1=0,b2=0,b3=0,b4=0,b5=0,b6=0,b7=0,b8=0,b9=0;
    float cA=0.f, cB=0.f;  // cell states

    // ================= init: pack weights, stage LDS =================
    if (wave == 0 || wave == 1){
#pragma unroll
        for (int li=0; li<2; ++li){
            const int L = wave*2 + li;
            const float* base = W_hh + (size_t)L*256*64;
#pragma unroll
            for (int d=0; d<8; ++d){
                wU[li*24 + 0*8 + d] = pack8(base + (size_t)(  0+lane)*64 + 8*d);  // i
                wU[li*24 + 1*8 + d] = pack8(base + (size_t)( 64+lane)*64 + 8*d);  // f
                wU[li*24 + 2*8 + d] = pack8(base + (size_t)(128+lane)*64 + 8*d);  // g
                *(uint4*)&s_wo[L][d][lane][0] = pack8(base + (size_t)(192+lane)*64 + 8*d); // o
            }
            if (lane<32){ s_h16hi[L][lane]=0u; s_h16lo[L][lane]=0u; }
        }
        // stage W_ih L4 groups: w0 -> grp 6,7 (rows 0..127); w1 -> grp 8,9 (rows 128..255)
#pragma unroll
        for (int g=0; g<2; ++g){
            const int row = wave*128 + g*64 + lane;
            const float* src = W_ih_rest + ((size_t)3*256 + row)*64;
            const int grp = 6 + wave*2 + g;
#pragma unroll
            for (int d=0; d<8; ++d)
                *(uint4*)&s_wih[grp][d][lane][0] = pack8(src + 8*d);
        }
        { int r0 = 4*256 + wave*128 + lane, r1 = r0 + 64;
          b0 = b_ih[r0]+b_hh[r0]; b1 = b_ih[r1]+b_hh[r1]; }
    } else if (wave == 2){
        const float* base = W_hh + (size_t)4*256*64;
#pragma unroll
        for (int d=0; d<8; ++d){
            wU[0*8+d] = pack8(base + (size_t)(  0+lane)*64 + 8*d);
            wU[1*8+d] = pack8(base + (size_t)( 64+lane)*64 + 8*d);
            wU[2*8+d] = pack8(base + (size_t)(128+lane)*64 + 8*d);
            *(uint4*)&s_wo[4][d][lane][0] = pack8(base + (size_t)(192+lane)*64 + 8*d);
        }
        if (lane<32){ s_h16hi[4][lane]=0u; s_h16lo[4][lane]=0u; }
        // L0 W_ih (K=45, pad to 48) -> regs: 4 groups x 6 uint4
#pragma unroll
        for (int g=0; g<4; ++g){
            const float* src = W_ih0 + (size_t)(g*64+lane)*45;
#pragma unroll
            for (int d=0; d<6; ++d){
                float e0=(8*d+0<45)?src[8*d+0]:0.f, e1=(8*d+1<45)?src[8*d+1]:0.f;
                float e2=(8*d+2<45)?src[8*d+2]:0.f, e3=(8*d+3<45)?src[8*d+3]:0.f;
                float e4=(8*d+4<45)?src[8*d+4]:0.f, e5=(8*d+5<45)?src[8*d+5]:0.f;
                float e6=(8*d+6<45)?src[8*d+6]:0.f, e7=(8*d+7<45)?src[8*d+7]:0.f;
                wU[24 + g*6 + d] = make_uint4(packh(e0,e1),packh(e2,e3),packh(e4,e5),packh(e6,e7));
            }
        }
        { int r;
          r=      lane; b0=b_ih[r]+b_hh[r];
          r=  64+lane;  b1=b_ih[r]+b_hh[r];
          r= 128+lane;  b2=b_ih[r]+b_hh[r];
          r= 192+lane;  b3=b_ih[r]+b_hh[r]; }
        // stage W_ih L2 groups {10,11} = rows 128..255 of layer 2
#pragma unroll
        for (int g=0; g<2; ++g){
            const int row = 128 + g*64 + lane;
            const float* src = W_ih_rest + ((size_t)1*256 + row)*64;
#pragma unroll
            for (int d=0; d<8; ++d)
                *(uint4*)&s_wih[g][d][lane][0] = pack8(src + 8*d);
        }
        { int r0=2*256+128+lane, r1=2*256+192+lane;
          b4=b_ih[r0]+b_hh[r0]; b5=b_ih[r1]+b_hh[r1]; }
        // zero x pad halves (cols 45..47, all buf/t, hi+lo)
        if (lane < 12){
            int bb=lane/6, t=(lane%6)/3, d=45+lane%3;
            ((__half*)&s_xhi[bb][t][0])[d]=__float2half(0.f);
            ((__half*)&s_xlo[bb][t][0])[d]=__float2half(0.f);
        }
    } else { // wave 3
#pragma unroll
        for (int g=0; g<6; ++g){
            const int ly  = (g<4) ? 1 : 2;
            const int row = (g<4) ? g*64+lane : (g-4)*64+lane;
            const float* src = W_ih_rest + ((size_t)(ly-1)*256 + row)*64;
#pragma unroll
            for (int d=0; d<8; ++d) wU[g*8+d] = pack8(src + 8*d);
        }
        { int r;
          r=1*256+  0+lane; b0=b_ih[r]+b_hh[r];
          r=1*256+ 64+lane; b1=b_ih[r]+b_hh[r];
          r=1*256+128+lane; b2=b_ih[r]+b_hh[r];
          r=1*256+192+lane; b3=b_ih[r]+b_hh[r];
          r=2*256+  0+lane; b4=b_ih[r]+b_hh[r];
          r=2*256+ 64+lane; b5=b_ih[r]+b_hh[r]; }
        // stage W_ih L3 groups {12..15}
#pragma unroll
        for (int g=0; g<4; ++g){
            const float* src = W_ih_rest + ((size_t)2*256 + g*64+lane)*64;
#pragma unroll
            for (int d=0; d<8; ++d) *(uint4*)&s_wih[2+g][d][lane][0] = pack8(src + 8*d);
        }
        { int r;
          r=3*256+  0+lane; b6=b_ih[r]+b_hh[r];
          r=3*256+ 64+lane; b7=b_ih[r]+b_hh[r];
          r=3*256+128+lane; b8=b_ih[r]+b_hh[r];
          r=3*256+192+lane; b9=b_ih[r]+b_hh[r]; }
    }
    __syncthreads();

// ---- recurrence step: layer L, wU base WB, LASTF=1 for layer 4 ----
#define R_STEP(L, WB, LASTF, T, C, CST) do{                                    \
    const int buf_ = (C)&1;                                                    \
    float xi_ = s_xg[buf_][L][T][      lane];                                  \
    float xf_ = s_xg[buf_][L][T][ 64 + lane];                                  \
    float xgg_= s_xg[buf_][L][T][128 + lane];                                  \
    float xo_ = s_xg[buf_][L][T][192 + lane];                                  \
    float ai_=0.f, af_=0.f, ag_=0.f, ao_=0.f;                                  \
    _Pragma("unroll")                                                          \
    for (int d_=0; d_<8; ++d_){                                                \
        uint4 hh_ = *(const uint4*)&s_h16hi[L][4*d_];                          \
        uint4 hl_ = *(const uint4*)&s_h16lo[L][4*d_];                          \
        uint4 wo_ = *(const uint4*)&s_wo[L][d_][lane][0];                      \
        DOT8(ai_, wU[(WB)+d_],    hh_, hl_);                                   \
        DOT8(af_, wU[(WB)+8+d_],  hh_, hl_);                                   \
        DOT8(ag_, wU[(WB)+16+d_], hh_, hl_);                                   \
        DOT8(ao_, wo_,            hh_, hl_);                                   \
    }                                                                          \
    float I_=sigmoid_(xi_+ai_), F_=sigmoid_(xf_+af_);                          \
    float G_=tanh_(xgg_+ag_),   O_=sigmoid_(xo_+ao_);                          \
    CST = fmaf(F_, CST, I_*G_);                                                \
    float h_ = O_*tanh_(CST);                                                  \
    __half hhi_=__float2half(h_);                                              \
    __half hlo_=__float2half(h_-__half2float(hhi_));                           \
    ((__half*)&s_h16hi[L][0])[lane]=hhi_;                                      \
    ((__half*)&s_h16lo[L][0])[lane]=hlo_;                                      \
    if (!(LASTF)){                                                             \
        ((__half*)&s_hhhi[(L)<4?(L):0][buf_][T][0])[lane]=hhi_;                \
        ((__half*)&s_hhlo[(L)<4?(L):0][buf_][T][0])[lane]=hlo_;                \
    } else if ((C)==NCH-1 && (T)==1){ hlast_g[lane]=h_; }                      \
}while(0)

// ---- xg GEMM blocks (4 or 2 row-groups sharing one h source) ----
#define G4(DMAX, WEXPR, HHI, HLO, XDST, B0_,B1_,B2_,B3_) do{                   \
    float a0_=(B0_), a1_=(B1_), a2_=(B2_), a3_=(B3_);                          \
    _Pragma("unroll")                                                          \
    for (int d_=0; d_<(DMAX); ++d_){                                           \
        uint4 hh_ = *(const uint4*)&(HHI)[4*d_];                               \
        uint4 hl_ = *(const uint4*)&(HLO)[4*d_];                               \
        uint4 wa_ = WEXPR(0,d_); DOT8(a0_, wa_, hh_, hl_);                     \
        uint4 wb_ = WEXPR(1,d_); DOT8(a1_, wb_, hh_, hl_);                     \
        uint4 wc_ = WEXPR(2,d_); DOT8(a2_, wc_, hh_, hl_);                     \
        uint4 wd_ = WEXPR(3,d_); DOT8(a3_, wd_, hh_, hl_);                     \
    }                                                                          \
    (XDST)[      lane]=a0_; (XDST)[ 64+lane]=a1_;                              \
    (XDST)[128+lane]=a2_;   (XDST)[192+lane]=a3_;                              \
}while(0)

#define G2(DMAX, WEXPR, HHI, HLO, XDST, ROWOFF, B0_,B1_) do{                   \
    float a0_=(B0_), a1_=(B1_);                                                \
    _Pragma("unroll")                                                          \
    for (int d_=0; d_<(DMAX); ++d_){                                           \
        uint4 hh_ = *(const uint4*)&(HHI)[4*d_];                               \
        uint4 hl_ = *(const uint4*)&(HLO)[4*d_];                               \
        uint4 wa_ = WEXPR(0,d_); DOT8(a0_, wa_, hh_, hl_);                     \
        uint4 wb_ = WEXPR(1,d_); DOT8(a1_, wb_, hh_, hl_);                     \
    }                                                                          \
    (XDST)[(ROWOFF)+lane]=a0_; (XDST)[(ROWOFF)+64+lane]=a1_;                   \
}while(0)

// weight selectors
#define W_L1(g,d)  wU[(g)*8+(d)]
#define W_L2R(g,d) wU[32+(g)*8+(d)]
#define W_L0(g,d)  wU[24+(g)*6+(d)]
#define W_L4R(g,d) wU[(g)*8+(d)]                                  /* unused name guard */
#define W_L2L(g,d) (*(const uint4*)&s_wih[(g)][d][lane][0])
#define W_L3(g,d)  (*(const uint4*)&s_wih[2+(g)][d][lane][0])
#define W_L4A(g,d) (*(const uint4*)&s_wih[6+(g)][d][lane][0])
#define W_L4B(g,d) (*(const uint4*)&s_wih[8+(g)][d][lane][0])

    // ================= supercycle loop =================
    for (int k=0; k<KMAX; ++k){
        if (wave == 0){
            const int c0=k-2, c1=k-4, cl=k-9;
            if (c0>=0 && c0<NCH) R_STEP(0,  0, 0, 0, c0, cA);
            if (c1>=0 && c1<NCH) R_STEP(1, 24, 0, 0, c1, cB);
            if (c0>=0 && c0<NCH) R_STEP(0,  0, 0, 1, c0, cA);
            if (c1>=0 && c1<NCH) R_STEP(1, 24, 0, 1, c1, cB);
            if (cl>=0 && cl<NCH){
                const int bl=cl&1;
                G2(8, W_L4A, &s_hhhi[3][bl][0][0], &s_hhlo[3][bl][0][0], &s_xg[bl][4][0][0], 0, b0,b1);
                G2(8, W_L4A, &s_hhhi[3][bl][1][0], &s_hhlo[3][bl][1][0], &s_xg[bl][4][1][0], 0, b0,b1);
            }
        } else if (wave == 1){
            const int c2=k-6, c3=k-8, cl=k-9;
            if (c2>=0 && c2<NCH) R_STEP(2,  0, 0, 0, c2, cA);
            if (c3>=0 && c3<NCH) R_STEP(3, 24, 0, 0, c3, cB);
            if (c2>=0 && c2<NCH) R_STEP(2,  0, 0, 1, c2, cA);
            if (c3>=0 && c3<NCH) R_STEP(3, 24, 0, 1, c3, cB);
            if (cl>=0 && cl<NCH){
                const int bl=cl&1;
                G2(8, W_L4B, &s_hhhi[3][bl][0][0], &s_hhlo[3][bl][0][0], &s_xg[bl][4][0][0], 128, b0,b1);
                G2(8, W_L4B, &s_hhhi[3][bl][1][0], &s_hhlo[3][bl][1][0], &s_xg[bl][4][1][0], 128, b0,b1);
            }
        } else if (wave == 2){
            // stage x chunk k (read at k+1)
            if (k < NCH){
                const int bufx = k & 1;
#pragma unroll
                for (int r=0; r<2; ++r){
                    const int i = lane + 64*r;
                    if (i < 90){
                        float v = x_s[(size_t)k*90 + i];
                        __half vh = __float2half(v);
                        __half vl = __float2half(v - __half2float(vh));
                        const int t = i/45, d = i - 45*t;
                        ((__half*)&s_xhi[bufx][t][0])[d] = vh;
                        ((__half*)&s_xlo[bufx][t][0])[d] = vl;
                    }
                }
            }
            const int c4=k-10, cg0=k-1, cg2=k-5;
            if (c4>=0 && c4<NCH)  R_STEP(4, 0, 1, 0, c4, cA);
            if (cg0>=0 && cg0<NCH){
                const int bg=cg0&1;
                G4(6, W_L0, &s_xhi[bg][0][0], &s_xlo[bg][0][0], &s_xg[bg][0][0][0], b0,b1,b2,b3);
                G4(6, W_L0, &s_xhi[bg][1][0], &s_xlo[bg][1][0], &s_xg[bg][0][1][0], b0,b1,b2,b3);
            }
            if (c4>=0 && c4<NCH)  R_STEP(4, 0, 1, 1, c4, cA);
            if (cg2>=0 && cg2<NCH){
                const int bg=cg2&1;
                G2(8, W_L2L, &s_hhhi[1][bg][0][0], &s_hhlo[1][bg][0][0], &s_xg[bg][2][0][0], 128, b4,b5);
                G2(8, W_L2L, &s_hhhi[1][bg][1][0], &s_hhlo[1][bg][1][0], &s_xg[bg][2][1][0], 128, b4,b5);
            }
        } else {
            const int cg1=k-3, cg2=k-5, cg3=k-7;
            if (cg1>=0 && cg1<NCH){
                const int bg=cg1&1;
                G4(8, W_L1, &s_hhhi[0][bg][0][0], &s_hhlo[0][bg][0][0], &s_xg[bg][1][0][0], b0,b1,b2,b3);
                G4(8, W_L1, &s_hhhi[0][bg][1][0], &s_hhlo[0][bg][1][0], &s_xg[bg][1][1][0], b0,b1,b2,b3);
            }
            if (cg2>=0 && cg2<NCH){
                const int bg=cg2&1;
                G2(8, W_L2R, &s_hhhi[1][bg][0][0], &s_hhlo[1][bg][0][0], &s_xg[bg][2][0][0], 0, b4,b5);
                G2(8, W_L2R, &s_hhhi[1][bg][1][0], &s_hhlo[1][bg][1][0], &s_xg[bg][2][1][0], 0, b4,b5);
            }
            if (cg3>=0 && cg3<NCH){
                const int bg=cg3&1;
                G4(8, W_L3, &s_hhhi[2][bg][0][0], &s_hhlo[2][bg][0][0], &s_xg[bg][3][0][0], b6,b7,b8,b9);
                G4(8, W_L3, &s_hhhi[2][bg][1][0], &s_hhlo[2][bg][1][0], &s_xg[bg][3][1][0], b6,b7,b8,b9);
            }
        }
        __syncthreads();
    }
}

// MLP head: features = gelu(last @ Wl^T + bl); out = relu(features @ Wo^T + bo)
// d_out layout: out[256*4] first, then features[256*128].
__global__ __launch_bounds__(128)
void head_kernel(const float* __restrict__ h_last,  // [256, 64]
                 const float* __restrict__ Wl,      // [128, 64]
                 const float* __restrict__ bl,      // [128]
                 const float* __restrict__ Wo,      // [4, 128]
                 const float* __restrict__ bo,      // [4]
                 float* __restrict__ d_out)
{
    __shared__ float s_last[HID];
    __shared__ float s_feat[128];
    const int s = blockIdx.x;
    const int j = threadIdx.x;

    if (j < HID) s_last[j] = h_last[(size_t)s * HID + j];
    __syncthreads();

    float acc = bl[j];
#pragma unroll
    for (int k = 0; k < HID; ++k)
        acc = fmaf(s_last[k], Wl[j * HID + k], acc);
    float f = 0.5f * acc * (1.0f + erff(acc * 0.70710678118654752440f));
    d_out[256 * 4 + s * 128 + j] = f;
    s_feat[j] = f;
    __syncthreads();

    if (j < 4) {
        float a = bo[j];
#pragma unroll
        for (int k = 0; k < 128; ++k)
            a = fmaf(s_feat[k], Wo[j * 128 + k], a);
        d_out[s * 4 + j] = fmaxf(a, 0.0f);
    }
}

extern "C" void kernel_launch(void* const* d_in, const int* in_sizes, int n_in,
                              void* d_out, int out_size, void* d_ws, size_t ws_size,
                              hipStream_t stream)
{
    const float* x         = (const float*)d_in[0];  // [256, 2048, 45]
    const float* W_ih0     = (const float*)d_in[1];  // [256, 45]
    const float* W_ih_rest = (const float*)d_in[2];  // [4, 256, 64]
    const float* W_hh      = (const float*)d_in[3];  // [5, 256, 64]
    const float* b_ih      = (const float*)d_in[4];  // [5, 256]
    const float* b_hh      = (const float*)d_in[5];  // [5, 256]
    const float* Wl        = (const float*)d_in[6];  // [128, 64]
    const float* bl        = (const float*)d_in[7];  // [128]
    const float* Wo        = (const float*)d_in[8];  // [4, 128]
    const float* bo        = (const float*)d_in[9];  // [4]

    float* h_last = (float*)d_ws;   // [256, 64] fp32

    lstm_pipe4<<<256, 256, 0, stream>>>(
        x, W_ih0, W_ih_rest, W_hh, b_ih, b_hh, h_last);
    head_kernel<<<256, 128, 0, stream>>>(h_last, Wl, bl, Wo, bo, (float*)d_out);
}